// Round 5
// baseline (121.288 us; speedup 1.0000x reference)
//
#include <hip/hip_runtime.h>

// INP=4096 MSK=64 HID=64 OUT=10  L1=64 L2=256 L3=128  B=16384  WVEC=4810
// Pipeline:
//   k_prep   : W1^T -> f16, W2/W3/W4 -> f16
//   k_gather : xm gather + layer1 dedup gather-sum (f16 W1T stream, 4 rows/wave)
//   k_hyper  : layers 2+3 (f16 MFMA, LDS h2/h3) + step-5 GEMM (A from L2,
//              2x reuse across sample halves) + fused per-sample einsums

typedef _Float16 f16;
typedef _Float16 f16x8 __attribute__((ext_vector_type(8)));
typedef _Float16 f16x4 __attribute__((ext_vector_type(4)));
typedef float    f32x4 __attribute__((ext_vector_type(4)));

#define NPAD 4864   // 4810 W4 rows padded to 76*64

// ---------------------------------------------------------------- prep
__global__ __launch_bounds__(256) void k_prep(
    const float* __restrict__ W1, const float* __restrict__ W2,
    const float* __restrict__ W3, const float* __restrict__ W4,
    f16* __restrict__ W1Th, f16* __restrict__ W2h,
    f16* __restrict__ W3h, f16* __restrict__ W4h)
{
    const int tid = blockIdx.x * 256 + threadIdx.x;
    const int stride = gridDim.x * 256;
    for (int e = tid; e < 4096 * 64; e += stride) {
        int j = e >> 6, i = e & 63;
        W1Th[e] = (f16)W1[(size_t)i * 4096 + j];
    }
    for (int e = tid; e < NPAD * 128; e += stride) {
        int n = e >> 7;
        W4h[e] = (n < 4810) ? (f16)W4[e] : (f16)0.f;
    }
    for (int e = tid; e < 256 * 64; e += stride)  W2h[e] = (f16)W2[e];
    for (int e = tid; e < 128 * 256; e += stride) W3h[e] = (f16)W3[e];
}

// ------------------------------------------- gather + layer 1 (dedup sum)
// 1024 blocks x 4 waves, 4 rows/wave (4 independent chains/thread for ILP).
// W1T stream is f16: halves the dominant L2->CU traffic.
__global__ __launch_bounds__(256) void k_gather(
    const float* __restrict__ data, const int* __restrict__ midx,
    const f16* __restrict__ W1Th, const float* __restrict__ b1,
    float* __restrict__ xm_out, f16* __restrict__ h1h)
{
    __shared__ int idx_s[16 * 64];
    const int t = threadIdx.x;
    const int row0 = blockIdx.x * 16;

    for (int e = t; e < 16 * 64; e += 256)
        idx_s[e] = midx[(size_t)row0 * 64 + e];
    __syncthreads();

    const int wv = t >> 6, lane = t & 63;
    const int r0 = 4 * wv;

    // xm gather (1 random 4B load per row per lane; lines are the HBM floor)
    #pragma unroll
    for (int k = 0; k < 4; ++k) {
        const int r = r0 + k;
        const int gi = idx_s[r * 64 + lane];
        xm_out[(size_t)(row0 + r) * 64 + lane] = data[(size_t)(row0 + r) * 4096 + gi];
    }

    // layer 1: deduped gather-sum of W1T rows (sorted -> adjacent-equal skip)
    const float b1v = b1[lane];
    float acc[4] = {b1v, b1v, b1v, b1v};
    int prev[4] = {-1, -1, -1, -1};
    #pragma unroll 8
    for (int i = 0; i < 64; ++i) {
        #pragma unroll
        for (int k = 0; k < 4; ++k) {
            const int cur = idx_s[(r0 + k) * 64 + i];
            const float wv_ = (float)W1Th[cur * 64 + lane];
            acc[k] += (cur != prev[k]) ? wv_ : 0.f;
            prev[k] = cur;
        }
    }
    #pragma unroll
    for (int k = 0; k < 4; ++k)
        h1h[(size_t)(row0 + r0 + k) * 64 + lane] = (f16)fmaxf(acc[k], 0.f);
}

// ------------------- fused: layers 2+3 + W4 GEMM + per-sample epilogues
// 256 blocks x 512 thr (8 waves), 64 samples/block (grid == CU count).
// Wave (rs = w>>2, cw = w&3): sample half rs (2 bfrag sets u=0,1 of 16),
// chunk group cw. A-fragments loaded once, used for both sample sets.
__global__ __launch_bounds__(512, 2) void k_hyper(
    const float* __restrict__ xmg, const f16* __restrict__ h1h,
    const f16* __restrict__ W2h, const float* __restrict__ b2,
    const f16* __restrict__ W3h, const float* __restrict__ b3,
    const f16* __restrict__ W4h, const float* __restrict__ b4,
    float* __restrict__ out)
{
    __shared__ __align__(16) float b4_s[NPAD];      // 19.5 KB
    __shared__ __align__(16) f16 h2_s[64 * 256];    // 32 KB (swizzled)
    __shared__ __align__(16) f16 h3_s[64 * 128];    // 16 KB (swizzled)
    __shared__ __align__(16) float hid_s[64 * 68];  // 17.4 KB
    __shared__ __align__(16) float res_s[64 * 12];  // 3 KB

    const int t = threadIdx.x, w = t >> 6, lane = t & 63;
    const int lr = lane & 15, g = lane >> 4;
    const int rs = w >> 2, cw = w & 3;
    const int row0 = blockIdx.x * 64;
    const f32x4 zero = {0.f, 0.f, 0.f, 0.f};
    char* h2b = (char*)h2_s;
    char* h3b = (char*)h3_s;

    for (int i = t; i < NPAD; i += 512)
        b4_s[i] = (i < 4810) ? b4[i] : 0.f;

    // ---------------- layer 2: wave w owns n in [32w,32w+32), K=64
    {
        f16x8 a2[2][2], bh[4][2];
        #pragma unroll
        for (int mt = 0; mt < 2; ++mt)
            #pragma unroll
            for (int kk = 0; kk < 2; ++kk)
                a2[mt][kk] = *(const f16x8*)&W2h[(32 * w + 16 * mt + lr) * 64 + 32 * kk + 8 * g];
        #pragma unroll
        for (int rt = 0; rt < 4; ++rt)
            #pragma unroll
            for (int kk = 0; kk < 2; ++kk)
                bh[rt][kk] = *(const f16x8*)&h1h[((size_t)row0 + 16 * rt + lr) * 64 + 32 * kk + 8 * g];

        f32x4 acc2[2][4];
        #pragma unroll
        for (int mt = 0; mt < 2; ++mt)
            #pragma unroll
            for (int rt = 0; rt < 4; ++rt)
                acc2[mt][rt] = __builtin_amdgcn_mfma_f32_16x16x32_f16(a2[mt][0], bh[rt][0], zero, 0, 0, 0);
        #pragma unroll
        for (int mt = 0; mt < 2; ++mt)
            #pragma unroll
            for (int rt = 0; rt < 4; ++rt)
                acc2[mt][rt] = __builtin_amdgcn_mfma_f32_16x16x32_f16(a2[mt][1], bh[rt][1], acc2[mt][rt], 0, 0, 0);

        #pragma unroll
        for (int mt = 0; mt < 2; ++mt) {
            const f32x4 bv = *(const f32x4*)&b2[32 * w + 16 * mt + 4 * g];
            #pragma unroll
            for (int rt = 0; rt < 4; ++rt) {
                const int s = 16 * rt + lr;
                f16x4 hv;
                #pragma unroll
                for (int q = 0; q < 4; ++q)
                    hv[q] = (f16)fmaxf(acc2[mt][rt][q] + bv[q], 0.f);
                const int byte = (s * 512 + (32 * w + 16 * mt + 4 * g) * 2) ^ ((s & 7) << 4);
                *(f16x4*)(h2b + byte) = hv;
            }
        }
    }
    __syncthreads();

    // ---------------- layer 3: wave w owns n in [16w,16w+16), K=256
    {
        f32x4 acc3[4] = {zero, zero, zero, zero};
        #pragma unroll 2
        for (int kk = 0; kk < 8; ++kk) {
            const f16x8 a3 = *(const f16x8*)&W3h[(16 * w + lr) * 256 + 32 * kk + 8 * g];
            #pragma unroll
            for (int rt = 0; rt < 4; ++rt) {
                const int s = 16 * rt + lr;
                const int byte = (s * 512 + (32 * kk + 8 * g) * 2) ^ ((s & 7) << 4);
                const f16x8 bb = *(const f16x8*)(h2b + byte);
                acc3[rt] = __builtin_amdgcn_mfma_f32_16x16x32_f16(a3, bb, acc3[rt], 0, 0, 0);
            }
        }
        const f32x4 bv3 = *(const f32x4*)&b3[16 * w + 4 * g];
        #pragma unroll
        for (int rt = 0; rt < 4; ++rt) {
            const int s = 16 * rt + lr;
            f16x4 hv;
            #pragma unroll
            for (int q = 0; q < 4; ++q)
                hv[q] = (f16)fmaxf(acc3[rt][q] + bv3[q], 0.f);
            const int byte = (s * 256 + (16 * w + 4 * g) * 2) ^ ((s & 7) << 4);
            *(f16x4*)(h3b + byte) = hv;
        }
    }
    __syncthreads();

    // B-fragments from LDS h3 (chunk-invariant), 2 sample sets per wave
    f16x8 bfrag[2][4];
    #pragma unroll
    for (int u = 0; u < 2; ++u)
        #pragma unroll
        for (int kk = 0; kk < 4; ++kk) {
            const int s = 32 * rs + 16 * u + lr;
            const int byte = (s * 256 + (32 * kk + 8 * g) * 2) ^ ((s & 7) << 4);
            bfrag[u][kk] = *(const f16x8*)(h3b + byte);
        }

    // xm registers: xm[sample][16mt+4g .. +4]
    f32x4 xmr[2][4];
    #pragma unroll
    for (int u = 0; u < 2; ++u)
        #pragma unroll
        for (int mt = 0; mt < 4; ++mt)
            xmr[u][mt] = *(const f32x4*)&xmg[((size_t)row0 + 32 * rs + 16 * u + lr) * 64 + 16 * mt + 4 * g];

    // ---------------- inp_w chunks: c = cw + 4j -> hid_s[sample][c]
    for (int j = 0; j < 16; ++j) {
        const int c = cw + 4 * j;
        const f16* Ab = W4h + (size_t)(64 * c) * 128;
        f16x8 a[4][4];                       // [kk][mt]
        #pragma unroll
        for (int mt = 0; mt < 4; ++mt)
            a[0][mt] = *(const f16x8*)&Ab[(16 * mt + lr) * 128 + 8 * g];
        #pragma unroll
        for (int mt = 0; mt < 4; ++mt)
            a[1][mt] = *(const f16x8*)&Ab[(16 * mt + lr) * 128 + 32 + 8 * g];

        f32x4 acc[4][2];
        #pragma unroll
        for (int kk = 0; kk < 4; ++kk) {
            if (kk < 2) {
                #pragma unroll
                for (int mt = 0; mt < 4; ++mt)
                    a[kk + 2][mt] = *(const f16x8*)&Ab[(16 * mt + lr) * 128 + 32 * (kk + 2) + 8 * g];
            }
            #pragma unroll
            for (int mt = 0; mt < 4; ++mt)
                #pragma unroll
                for (int u = 0; u < 2; ++u)
                    acc[mt][u] = (kk == 0)
                        ? __builtin_amdgcn_mfma_f32_16x16x32_f16(a[0][mt], bfrag[u][0], zero, 0, 0, 0)
                        : __builtin_amdgcn_mfma_f32_16x16x32_f16(a[kk][mt], bfrag[u][kk], acc[mt][u], 0, 0, 0);
        }

        f32x4 bv[4];
        #pragma unroll
        for (int mt = 0; mt < 4; ++mt)
            bv[mt] = *(const f32x4*)&b4_s[64 * c + 16 * mt + 4 * g];

        #pragma unroll
        for (int u = 0; u < 2; ++u) {
            float s = 0.f;
            #pragma unroll
            for (int mt = 0; mt < 4; ++mt)
                #pragma unroll
                for (int q = 0; q < 4; ++q)
                    s += (acc[mt][u][q] + bv[mt][q]) * xmr[u][mt][q];
            s += __shfl_xor(s, 16);
            s += __shfl_xor(s, 32);
            if (g == 0) hid_s[(32 * rs + 16 * u + lr) * 68 + c] = s;
        }
    }
    __syncthreads();

    // ---------------- chunk 64: inp_b (wave handles h-tile = cw) + ReLU
    {
        const f16* Ab = W4h + (size_t)4096 * 128;
        f16x8 a[4];
        #pragma unroll
        for (int kk = 0; kk < 4; ++kk)
            a[kk] = *(const f16x8*)&Ab[(16 * cw + lr) * 128 + 32 * kk + 8 * g];
        #pragma unroll
        for (int u = 0; u < 2; ++u) {
            f32x4 acc = zero;
            #pragma unroll
            for (int kk = 0; kk < 4; ++kk)
                acc = __builtin_amdgcn_mfma_f32_16x16x32_f16(a[kk], bfrag[u][kk], acc, 0, 0, 0);
            const int s = 32 * rs + 16 * u + lr;
            const int hb = 16 * cw + 4 * g;
            f32x4 hv = *(const f32x4*)&hid_s[s * 68 + hb];
            const f32x4 bv = *(const f32x4*)&b4_s[4096 + hb];
            #pragma unroll
            for (int q = 0; q < 4; ++q)
                hv[q] = fmaxf(hv[q] + acc[q] + bv[q], 0.f);
            *(f32x4*)&hid_s[s * 68 + hb] = hv;
        }
    }
    __syncthreads();

    // hid registers for the out-phase epilogue
    f32x4 hidr[2][4];
    #pragma unroll
    for (int u = 0; u < 2; ++u)
        #pragma unroll
        for (int mt = 0; mt < 4; ++mt)
            hidr[u][mt] = *(const f32x4*)&hid_s[(32 * rs + 16 * u + lr) * 68 + 16 * mt + 4 * g];

    // ---------------- out_w chunks: c in {65+cw, 69+cw, 73+cw} ∩ [65,74]
    for (int c = 65 + cw; c <= 74; c += 4) {
        const f16* Ab = W4h + (size_t)(64 * c) * 128;
        f16x8 a[4][4];
        #pragma unroll
        for (int mt = 0; mt < 4; ++mt)
            a[0][mt] = *(const f16x8*)&Ab[(16 * mt + lr) * 128 + 8 * g];
        #pragma unroll
        for (int mt = 0; mt < 4; ++mt)
            a[1][mt] = *(const f16x8*)&Ab[(16 * mt + lr) * 128 + 32 + 8 * g];

        f32x4 acc[4][2];
        #pragma unroll
        for (int kk = 0; kk < 4; ++kk) {
            if (kk < 2) {
                #pragma unroll
                for (int mt = 0; mt < 4; ++mt)
                    a[kk + 2][mt] = *(const f16x8*)&Ab[(16 * mt + lr) * 128 + 32 * (kk + 2) + 8 * g];
            }
            #pragma unroll
            for (int mt = 0; mt < 4; ++mt)
                #pragma unroll
                for (int u = 0; u < 2; ++u)
                    acc[mt][u] = (kk == 0)
                        ? __builtin_amdgcn_mfma_f32_16x16x32_f16(a[0][mt], bfrag[u][0], zero, 0, 0, 0)
                        : __builtin_amdgcn_mfma_f32_16x16x32_f16(a[kk][mt], bfrag[u][kk], acc[mt][u], 0, 0, 0);
        }

        f32x4 bv[4];
        #pragma unroll
        for (int mt = 0; mt < 4; ++mt)
            bv[mt] = *(const f32x4*)&b4_s[64 * c + 16 * mt + 4 * g];

        #pragma unroll
        for (int u = 0; u < 2; ++u) {
            float s = 0.f;
            #pragma unroll
            for (int mt = 0; mt < 4; ++mt)
                #pragma unroll
                for (int q = 0; q < 4; ++q)
                    s += (acc[mt][u][q] + bv[mt][q]) * hidr[u][mt][q];
            s += __shfl_xor(s, 16);
            s += __shfl_xor(s, 32);
            if (g == 0) res_s[(32 * rs + 16 * u + lr) * 12 + (c - 65)] = s;
        }
    }
    __syncthreads();

    // ---------------- chunk 75: out_b (rows 4800..4809)
    if (cw == 3) {
        const f16* Ab = W4h + (size_t)4800 * 128;
        f16x8 a[4];
        #pragma unroll
        for (int kk = 0; kk < 4; ++kk)
            a[kk] = *(const f16x8*)&Ab[lr * 128 + 32 * kk + 8 * g];
        #pragma unroll
        for (int u = 0; u < 2; ++u) {
            f32x4 acc = zero;
            #pragma unroll
            for (int kk = 0; kk < 4; ++kk)
                acc = __builtin_amdgcn_mfma_f32_16x16x32_f16(a[kk], bfrag[u][kk], acc, 0, 0, 0);
            const int si = 32 * rs + 16 * u + lr;
            #pragma unroll
            for (int q = 0; q < 4; ++q) {
                const int o = 4 * g + q;
                if (o < 10)
                    res_s[si * 12 + o] += acc[q] + b4_s[4800 + o];
            }
        }
    }
    __syncthreads();

    for (int e = t; e < 640; e += 512)
        out[(size_t)row0 * 10 + e] = res_s[(e / 10) * 12 + (e % 10)];
}

// ---------------------------------------------------------------- launcher
extern "C" void kernel_launch(void* const* d_in, const int* in_sizes, int n_in,
                              void* d_out, int out_size, void* d_ws, size_t ws_size,
                              hipStream_t stream)
{
    const float* data = (const float*)d_in[0];
    const int*   midx = (const int*)d_in[1];
    const float* W1   = (const float*)d_in[2];
    const float* b1   = (const float*)d_in[3];
    const float* W2   = (const float*)d_in[4];
    const float* b2   = (const float*)d_in[5];
    const float* W3   = (const float*)d_in[6];
    const float* b3   = (const float*)d_in[7];
    const float* W4   = (const float*)d_in[8];
    const float* b4   = (const float*)d_in[9];
    float* out = (float*)d_out;

    float* xm_ws = (float*)d_ws;                        // 1048576 f32
    f16*   W1Th  = (f16*)(xm_ws + (size_t)16384 * 64);  // 262144 f16
    f16*   h1h   = W1Th + (size_t)4096 * 64;            // 1048576 f16
    f16*   W4h   = h1h + (size_t)16384 * 64;            // 622592 f16
    f16*   W2h   = W4h + (size_t)NPAD * 128;            // 16384 f16
    f16*   W3h   = W2h + 256 * 64;                      // 32768 f16

    k_prep  <<<512, 256, 0, stream>>>(W1, W2, W3, W4, W1Th, W2h, W3h, W4h);
    k_gather<<<1024, 256, 0, stream>>>(data, midx, W1Th, b1, xm_ws, h1h);
    k_hyper <<<256, 512, 0, stream>>>(xm_ws, h1h, W2h, b2, W3h, b3, W4h, b4, out);
}

// Round 6
// 111.567 us; speedup vs baseline: 1.0871x; 1.0871x over previous
//
#include <hip/hip_runtime.h>

// INP=4096 MSK=64 HID=64 OUT=10  L1=64 L2=256 L3=128  B=16384  WVEC=4810
// Pipeline:
//   k_prep : W1^T -> f16, W2/W3/W4 -> f16
//   k_main : ONE kernel per 64 samples:
//     xm random-gather issued first (regs, drains at first barrier ->
//     overlaps W1T/layers/GEMM chip-wide), lane-parallel W1T dedup-sum,
//     layers 2+3 f16 MFMA (LDS h1/h2/h3, XOR-swizzled), W4 GEMM from L2
//     with 2x A-reuse, fused per-sample einsum epilogues.

typedef _Float16 f16;
typedef _Float16 f16x8 __attribute__((ext_vector_type(8)));
typedef _Float16 f16x4 __attribute__((ext_vector_type(4)));
typedef float    f32x4 __attribute__((ext_vector_type(4)));

#define NPAD 4864   // 4810 W4 rows padded to 76*64

// ---------------------------------------------------------------- prep
__global__ __launch_bounds__(256) void k_prep(
    const float* __restrict__ W1, const float* __restrict__ W2,
    const float* __restrict__ W3, const float* __restrict__ W4,
    f16* __restrict__ W1Th, f16* __restrict__ W2h,
    f16* __restrict__ W3h, f16* __restrict__ W4h)
{
    const int tid = blockIdx.x * 256 + threadIdx.x;
    const int stride = gridDim.x * 256;
    for (int e = tid; e < 4096 * 64; e += stride) {
        int j = e >> 6, i = e & 63;
        W1Th[e] = (f16)W1[(size_t)i * 4096 + j];
    }
    for (int e = tid; e < NPAD * 128; e += stride) {
        int n = e >> 7;
        W4h[e] = (n < 4810) ? (f16)W4[e] : (f16)0.f;
    }
    for (int e = tid; e < 256 * 64; e += stride)  W2h[e] = (f16)W2[e];
    for (int e = tid; e < 128 * 256; e += stride) W3h[e] = (f16)W3[e];
}

// ---------------------------------------------------------------- main
// 256 blocks x 512 thr (8 waves), 64 samples/block, 2 blocks/CU (75KB LDS).
// LDS unions:
//   uA: phase A = h2 (32K, swizzled) + h1 (8K @32768, swizzled)
//       phase B = xm[64][68] f32 (17408) + hid[64][68] f32 (@17408)
//                 + res[64][12] f32 (@34816)
//   uB: idx[64][64] i32  ->  h3 (16K, swizzled)  (idx dead after xm issue/W1T)
__global__ __launch_bounds__(512, 2) void k_main(
    const float* __restrict__ data, const int* __restrict__ midx,
    const f16* __restrict__ W1Th, const float* __restrict__ b1,
    const f16* __restrict__ W2h, const float* __restrict__ b2,
    const f16* __restrict__ W3h, const float* __restrict__ b3,
    const f16* __restrict__ W4h, const float* __restrict__ b4,
    float* __restrict__ out)
{
    __shared__ __align__(16) float b4_s[NPAD];   // 19456 B
    __shared__ __align__(16) char uA[40960];
    __shared__ __align__(16) char uB[16384];

    const int t = threadIdx.x, w = t >> 6, lane = t & 63;
    const int lr = lane & 15, g = lane >> 4;
    const int rs = w >> 2, cw = w & 3;
    const int row0 = blockIdx.x * 64;
    const f32x4 zero = {0.f, 0.f, 0.f, 0.f};

    int* idx_s = (int*)uB;
    char* h2b  = uA;
    char* h1b  = uA + 32768;
    char* h3b  = uB;
    float* xm_s  = (float*)uA;             // [64][68]
    float* hid_s = (float*)(uA + 17408);   // [64][68]
    float* res_s = (float*)(uA + 34816);   // [64][12]

    // ---- phase 1: mask indices -> LDS
    for (int e = t; e < 4096; e += 512)
        idx_s[e] = midx[(size_t)row0 * 64 + e];
    __syncthreads();

    // ---- phase 2: issue xm random gather (drains at h1 barrier; the HBM
    // random-read pipe overlaps compute chip-wide via staggered blocks)
    float xr[8];
    #pragma unroll
    for (int k = 0; k < 8; ++k) {
        const int e = k * 512 + t;           // e = s*64 + m
        xr[k] = data[(size_t)(row0 + (e >> 6)) * 4096 + idx_s[e]];
    }
    // b4 staging (coalesced, cheap)
    for (int i = t; i < NPAD; i += 512)
        b4_s[i] = (i < 4810) ? b4[i] : 0.f;

    // ---- phase 3: layer 1 dedup gather-sum, lane-parallel (wave-local)
    // wave w: samples 8w..8w+7; lane (i4=g, h16=lr): indices i4*16+t,
    // hidden slice h16*4..+4; shuffle-reduce over i4.
    {
        const f32x4 b1v = *(const f32x4*)&b1[lr * 4];
        for (int p = 0; p < 4; ++p) {
            const int s0 = 8 * w + 2 * p, s1 = s0 + 1;
            f32x4 a0 = zero, a1 = zero;
            #pragma unroll
            for (int tt = 0; tt < 16; ++tt) {
                const int i = g * 16 + tt;
                const int c0 = idx_s[s0 * 64 + i];
                const int q0 = (i > 0) ? idx_s[s0 * 64 + i - 1] : -1;
                const int c1 = idx_s[s1 * 64 + i];
                const int q1 = (i > 0) ? idx_s[s1 * 64 + i - 1] : -1;
                const f16x4 w0 = *(const f16x4*)&W1Th[c0 * 64 + lr * 4];
                const f16x4 w1 = *(const f16x4*)&W1Th[c1 * 64 + lr * 4];
                #pragma unroll
                for (int q = 0; q < 4; ++q) {
                    a0[q] += (c0 != q0) ? (float)w0[q] : 0.f;
                    a1[q] += (c1 != q1) ? (float)w1[q] : 0.f;
                }
            }
            #pragma unroll
            for (int q = 0; q < 4; ++q) {
                a0[q] += __shfl_xor(a0[q], 16);
                a0[q] += __shfl_xor(a0[q], 32);
                a1[q] += __shfl_xor(a1[q], 16);
                a1[q] += __shfl_xor(a1[q], 32);
            }
            if (g == 0) {
                f16x4 h0, h1v;
                #pragma unroll
                for (int q = 0; q < 4; ++q) {
                    h0[q]  = (f16)fmaxf(a0[q] + b1v[q], 0.f);
                    h1v[q] = (f16)fmaxf(a1[q] + b1v[q], 0.f);
                }
                const int byte0 = (s0 * 128 + lr * 8) ^ ((s0 & 7) << 4);
                const int byte1 = (s1 * 128 + lr * 8) ^ ((s1 & 7) << 4);
                *(f16x4*)(h1b + byte0) = h0;
                *(f16x4*)(h1b + byte1) = h1v;
            }
        }
    }
    __syncthreads();   // h1 ready; xm/b4 loads drain here

    // ---- phase 4: layer 2 (wave w owns n in [32w,32w+32), K=64)
    {
        f16x8 a2[2][2], bh[4][2];
        #pragma unroll
        for (int mt = 0; mt < 2; ++mt)
            #pragma unroll
            for (int kk = 0; kk < 2; ++kk)
                a2[mt][kk] = *(const f16x8*)&W2h[(32 * w + 16 * mt + lr) * 64 + 32 * kk + 8 * g];
        #pragma unroll
        for (int rt = 0; rt < 4; ++rt)
            #pragma unroll
            for (int kk = 0; kk < 2; ++kk) {
                const int s = 16 * rt + lr;
                const int byte = (s * 128 + (32 * kk + 8 * g) * 2) ^ ((s & 7) << 4);
                bh[rt][kk] = *(const f16x8*)(h1b + byte);
            }

        f32x4 acc2[2][4];
        #pragma unroll
        for (int mt = 0; mt < 2; ++mt)
            #pragma unroll
            for (int rt = 0; rt < 4; ++rt)
                acc2[mt][rt] = __builtin_amdgcn_mfma_f32_16x16x32_f16(a2[mt][0], bh[rt][0], zero, 0, 0, 0);
        #pragma unroll
        for (int mt = 0; mt < 2; ++mt)
            #pragma unroll
            for (int rt = 0; rt < 4; ++rt)
                acc2[mt][rt] = __builtin_amdgcn_mfma_f32_16x16x32_f16(a2[mt][1], bh[rt][1], acc2[mt][rt], 0, 0, 0);

        #pragma unroll
        for (int mt = 0; mt < 2; ++mt) {
            const f32x4 bv = *(const f32x4*)&b2[32 * w + 16 * mt + 4 * g];
            #pragma unroll
            for (int rt = 0; rt < 4; ++rt) {
                const int s = 16 * rt + lr;
                f16x4 hv;
                #pragma unroll
                for (int q = 0; q < 4; ++q)
                    hv[q] = (f16)fmaxf(acc2[mt][rt][q] + bv[q], 0.f);
                const int byte = (s * 512 + (32 * w + 16 * mt + 4 * g) * 2) ^ ((s & 7) << 4);
                *(f16x4*)(h2b + byte) = hv;
            }
        }
    }
    __syncthreads();

    // ---- phase 5: layer 3 (wave w owns n in [16w,16w+16), K=256)
    {
        f32x4 acc3[4] = {zero, zero, zero, zero};
        #pragma unroll 2
        for (int kk = 0; kk < 8; ++kk) {
            const f16x8 a3 = *(const f16x8*)&W3h[(16 * w + lr) * 256 + 32 * kk + 8 * g];
            #pragma unroll
            for (int rt = 0; rt < 4; ++rt) {
                const int s = 16 * rt + lr;
                const int byte = (s * 512 + (32 * kk + 8 * g) * 2) ^ ((s & 7) << 4);
                const f16x8 bb = *(const f16x8*)(h2b + byte);
                acc3[rt] = __builtin_amdgcn_mfma_f32_16x16x32_f16(a3, bb, acc3[rt], 0, 0, 0);
            }
        }
        const f32x4 bv3 = *(const f32x4*)&b3[16 * w + 4 * g];
        #pragma unroll
        for (int rt = 0; rt < 4; ++rt) {
            const int s = 16 * rt + lr;
            f16x4 hv;
            #pragma unroll
            for (int q = 0; q < 4; ++q)
                hv[q] = (f16)fmaxf(acc3[rt][q] + bv3[q], 0.f);
            const int byte = (s * 256 + (16 * w + 4 * g) * 2) ^ ((s & 7) << 4);
            *(f16x4*)(h3b + byte) = hv;
        }
    }
    __syncthreads();   // h3 ready; h2/idx now dead

    // ---- phase 6: xm regs -> LDS; B-fragments from h3
    #pragma unroll
    for (int k = 0; k < 8; ++k) {
        const int e = k * 512 + t;
        xm_s[(e >> 6) * 68 + (e & 63)] = xr[k];
    }
    f16x8 bfrag[2][4];
    #pragma unroll
    for (int u = 0; u < 2; ++u)
        #pragma unroll
        for (int kk = 0; kk < 4; ++kk) {
            const int s = 32 * rs + 16 * u + lr;
            const int byte = (s * 256 + (32 * kk + 8 * g) * 2) ^ ((s & 7) << 4);
            bfrag[u][kk] = *(const f16x8*)(h3b + byte);
        }
    __syncthreads();   // xm_s ready

    f32x4 xmr[2][4];
    #pragma unroll
    for (int u = 0; u < 2; ++u)
        #pragma unroll
        for (int mt = 0; mt < 4; ++mt)
            xmr[u][mt] = *(const f32x4*)&xm_s[(32 * rs + 16 * u + lr) * 68 + 16 * mt + 4 * g];

    // ---- inp_w chunks: c = cw + 4j -> hid_s[sample][c]
    for (int j = 0; j < 16; ++j) {
        const int c = cw + 4 * j;
        const f16* Ab = W4h + (size_t)(64 * c) * 128;
        f16x8 a[4][4];                       // [kk][mt]
        #pragma unroll
        for (int mt = 0; mt < 4; ++mt)
            a[0][mt] = *(const f16x8*)&Ab[(16 * mt + lr) * 128 + 8 * g];
        #pragma unroll
        for (int mt = 0; mt < 4; ++mt)
            a[1][mt] = *(const f16x8*)&Ab[(16 * mt + lr) * 128 + 32 + 8 * g];

        f32x4 acc[4][2];
        #pragma unroll
        for (int kk = 0; kk < 4; ++kk) {
            if (kk < 2) {
                #pragma unroll
                for (int mt = 0; mt < 4; ++mt)
                    a[kk + 2][mt] = *(const f16x8*)&Ab[(16 * mt + lr) * 128 + 32 * (kk + 2) + 8 * g];
            }
            #pragma unroll
            for (int mt = 0; mt < 4; ++mt)
                #pragma unroll
                for (int u = 0; u < 2; ++u)
                    acc[mt][u] = (kk == 0)
                        ? __builtin_amdgcn_mfma_f32_16x16x32_f16(a[0][mt], bfrag[u][0], zero, 0, 0, 0)
                        : __builtin_amdgcn_mfma_f32_16x16x32_f16(a[kk][mt], bfrag[u][kk], acc[mt][u], 0, 0, 0);
        }

        f32x4 bv[4];
        #pragma unroll
        for (int mt = 0; mt < 4; ++mt)
            bv[mt] = *(const f32x4*)&b4_s[64 * c + 16 * mt + 4 * g];

        #pragma unroll
        for (int u = 0; u < 2; ++u) {
            float s = 0.f;
            #pragma unroll
            for (int mt = 0; mt < 4; ++mt)
                #pragma unroll
                for (int q = 0; q < 4; ++q)
                    s += (acc[mt][u][q] + bv[mt][q]) * xmr[u][mt][q];
            s += __shfl_xor(s, 16);
            s += __shfl_xor(s, 32);
            if (g == 0) hid_s[(32 * rs + 16 * u + lr) * 68 + c] = s;
        }
    }
    __syncthreads();

    // ---- chunk 64: inp_b (wave handles h-tile = cw) + ReLU
    {
        const f16* Ab = W4h + (size_t)4096 * 128;
        f16x8 a[4];
        #pragma unroll
        for (int kk = 0; kk < 4; ++kk)
            a[kk] = *(const f16x8*)&Ab[(16 * cw + lr) * 128 + 32 * kk + 8 * g];
        #pragma unroll
        for (int u = 0; u < 2; ++u) {
            f32x4 acc = zero;
            #pragma unroll
            for (int kk = 0; kk < 4; ++kk)
                acc = __builtin_amdgcn_mfma_f32_16x16x32_f16(a[kk], bfrag[u][kk], acc, 0, 0, 0);
            const int s = 32 * rs + 16 * u + lr;
            const int hb = 16 * cw + 4 * g;
            f32x4 hv = *(const f32x4*)&hid_s[s * 68 + hb];
            const f32x4 bv = *(const f32x4*)&b4_s[4096 + hb];
            #pragma unroll
            for (int q = 0; q < 4; ++q)
                hv[q] = fmaxf(hv[q] + acc[q] + bv[q], 0.f);
            *(f32x4*)&hid_s[s * 68 + hb] = hv;
        }
    }
    __syncthreads();

    // hid registers for the out-phase epilogue
    f32x4 hidr[2][4];
    #pragma unroll
    for (int u = 0; u < 2; ++u)
        #pragma unroll
        for (int mt = 0; mt < 4; ++mt)
            hidr[u][mt] = *(const f32x4*)&hid_s[(32 * rs + 16 * u + lr) * 68 + 16 * mt + 4 * g];

    // ---- out_w chunks: c in {65+cw, 69+cw, 73+cw} ∩ [65,74]
    for (int c = 65 + cw; c <= 74; c += 4) {
        const f16* Ab = W4h + (size_t)(64 * c) * 128;
        f16x8 a[4][4];
        #pragma unroll
        for (int mt = 0; mt < 4; ++mt)
            a[0][mt] = *(const f16x8*)&Ab[(16 * mt + lr) * 128 + 8 * g];
        #pragma unroll
        for (int mt = 0; mt < 4; ++mt)
            a[1][mt] = *(const f16x8*)&Ab[(16 * mt + lr) * 128 + 32 + 8 * g];

        f32x4 acc[4][2];
        #pragma unroll
        for (int kk = 0; kk < 4; ++kk) {
            if (kk < 2) {
                #pragma unroll
                for (int mt = 0; mt < 4; ++mt)
                    a[kk + 2][mt] = *(const f16x8*)&Ab[(16 * mt + lr) * 128 + 32 * (kk + 2) + 8 * g];
            }
            #pragma unroll
            for (int mt = 0; mt < 4; ++mt)
                #pragma unroll
                for (int u = 0; u < 2; ++u)
                    acc[mt][u] = (kk == 0)
                        ? __builtin_amdgcn_mfma_f32_16x16x32_f16(a[0][mt], bfrag[u][0], zero, 0, 0, 0)
                        : __builtin_amdgcn_mfma_f32_16x16x32_f16(a[kk][mt], bfrag[u][kk], acc[mt][u], 0, 0, 0);
        }

        f32x4 bv[4];
        #pragma unroll
        for (int mt = 0; mt < 4; ++mt)
            bv[mt] = *(const f32x4*)&b4_s[64 * c + 16 * mt + 4 * g];

        #pragma unroll
        for (int u = 0; u < 2; ++u) {
            float s = 0.f;
            #pragma unroll
            for (int mt = 0; mt < 4; ++mt)
                #pragma unroll
                for (int q = 0; q < 4; ++q)
                    s += (acc[mt][u][q] + bv[mt][q]) * hidr[u][mt][q];
            s += __shfl_xor(s, 16);
            s += __shfl_xor(s, 32);
            if (g == 0) res_s[(32 * rs + 16 * u + lr) * 12 + (c - 65)] = s;
        }
    }
    __syncthreads();

    // ---- chunk 75: out_b (rows 4800..4809)
    if (cw == 3) {
        const f16* Ab = W4h + (size_t)4800 * 128;
        f16x8 a[4];
        #pragma unroll
        for (int kk = 0; kk < 4; ++kk)
            a[kk] = *(const f16x8*)&Ab[lr * 128 + 32 * kk + 8 * g];
        #pragma unroll
        for (int u = 0; u < 2; ++u) {
            f32x4 acc = zero;
            #pragma unroll
            for (int kk = 0; kk < 4; ++kk)
                acc = __builtin_amdgcn_mfma_f32_16x16x32_f16(a[kk], bfrag[u][kk], acc, 0, 0, 0);
            const int si = 32 * rs + 16 * u + lr;
            #pragma unroll
            for (int q = 0; q < 4; ++q) {
                const int o = 4 * g + q;
                if (o < 10)
                    res_s[si * 12 + o] += acc[q] + b4_s[4800 + o];
            }
        }
    }
    __syncthreads();

    for (int e = t; e < 640; e += 512)
        out[(size_t)row0 * 10 + e] = res_s[(e / 10) * 12 + (e % 10)];
}

// ---------------------------------------------------------------- launcher
extern "C" void kernel_launch(void* const* d_in, const int* in_sizes, int n_in,
                              void* d_out, int out_size, void* d_ws, size_t ws_size,
                              hipStream_t stream)
{
    const float* data = (const float*)d_in[0];
    const int*   midx = (const int*)d_in[1];
    const float* W1   = (const float*)d_in[2];
    const float* b1   = (const float*)d_in[3];
    const float* W2   = (const float*)d_in[4];
    const float* b2   = (const float*)d_in[5];
    const float* W3   = (const float*)d_in[6];
    const float* b3   = (const float*)d_in[7];
    const float* W4   = (const float*)d_in[8];
    const float* b4   = (const float*)d_in[9];
    float* out = (float*)d_out;

    f16* W1Th = (f16*)d_ws;                    // 262144 f16
    f16* W4h  = W1Th + (size_t)4096 * 64;      // 622592 f16
    f16* W2h  = W4h + (size_t)NPAD * 128;      // 16384 f16
    f16* W3h  = W2h + 256 * 64;                // 32768 f16

    k_prep<<<512, 256, 0, stream>>>(W1, W2, W3, W4, W1Th, W2h, W3h, W4h);
    k_main<<<256, 512, 0, stream>>>(data, midx, W1Th, b1, W2h, b2, W3h, b3,
                                    W4h, b4, out);
}